// Round 3
// baseline (495.195 us; speedup 1.0000x reference)
//
#include <hip/hip_runtime.h>
#include <stdint.h>

#define S_LEN 512
#define NT 9

typedef __attribute__((ext_vector_type(8)))  short          bf16x8;
typedef __attribute__((ext_vector_type(4)))  float          f32x4;
typedef __attribute__((ext_vector_type(16))) unsigned short u16x16;
typedef __attribute__((ext_vector_type(4)))  unsigned int   u32x4;

static __device__ __forceinline__ unsigned short f2bf(float f) {
    union { float f; unsigned u; } c; c.f = f;
    return (unsigned short)((c.u + 0x7fffu + ((c.u >> 16) & 1u)) >> 16); // RNE
}
static __device__ __forceinline__ float bf2f(unsigned short h) {
    union { unsigned u; float f; } c; c.u = ((unsigned)h) << 16;
    return c.f;
}
static __device__ __forceinline__ bf16x8 cvt8(const float* p) {
    f32x4 a = *(const f32x4*)p, b = *(const f32x4*)(p + 4);
    bf16x8 fr;
    fr[0]=(short)f2bf(a[0]); fr[1]=(short)f2bf(a[1]); fr[2]=(short)f2bf(a[2]); fr[3]=(short)f2bf(a[3]);
    fr[4]=(short)f2bf(b[0]); fr[5]=(short)f2bf(b[1]); fr[6]=(short)f2bf(b[2]); fr[7]=(short)f2bf(b[3]);
    return fr;
}
static __device__ __forceinline__ float sigf(float x) {
    return __builtin_amdgcn_rcpf(1.0f + __expf(-x));
}
static __device__ __forceinline__ float tanhf_(float x) {
    return 1.0f - 2.0f * __builtin_amdgcn_rcpf(1.0f + __expf(2.0f * x));
}
static __device__ __forceinline__ float sel4(f32x4 a, int l4) {
    float x01 = (l4 & 1) ? a[1] : a[0];
    float x23 = (l4 & 1) ? a[3] : a[2];
    return (l4 & 2) ? x23 : x01;
}

// Raw workgroup barrier that waits ONLY LDS ops (lgkmcnt) — global loads stay
// in flight across it (unlike __syncthreads(), which drains vmcnt(0) and
// kills software prefetching across steps).
static __device__ __forceinline__ void wg_barrier_lds() {
    asm volatile("s_waitcnt lgkmcnt(0)" ::: "memory");
    __builtin_amdgcn_s_barrier();
    asm volatile("" ::: "memory");
}

// ---------------------------------------------------------------------------
// Kernel 1: xg = emb[x] @ W_ih^T + b, stored bf16 in the k_lstm-friendly order:
//   xg[s][dir][bt(32 tiles of 4 rows)][w(8)][l15(16)][q(4)][j(4)]
// Raw barriers + depth-2 embed-row prefetch keep HBM loads in flight.
// ---------------------------------------------------------------------------
__global__ __launch_bounds__(512) void k_xg(
    const int* __restrict__ x, const float* __restrict__ embed,
    const float* __restrict__ Wf, const float* __restrict__ bF,
    const float* __restrict__ Wb, const float* __restrict__ bB,
    unsigned short* __restrict__ xg)
{
    const int dir = blockIdx.y;
    const float* __restrict__ W    = dir ? Wb : Wf;
    const float* __restrict__ bias = dir ? bB : bF;
    const int tid = threadIdx.x;
    const int wv = tid >> 6, L = tid & 63, l15 = L & 15, l4 = L >> 4;
    const int s0 = blockIdx.x * 4;

    // W_ih B-fragments in registers (64 VGPR)
    bf16x8 Bf[4][4];
    float  bq[4];
#pragma unroll
    for (int q = 0; q < 4; ++q) {
        const int gate = q * 128 + wv * 16 + l15;
        bq[q] = bias[gate];
#pragma unroll
        for (int kt = 0; kt < 4; ++kt)
            Bf[q][kt] = cvt8(W + gate * 128 + kt * 32 + l4 * 8);
    }

    __shared__ int tokL[512];                 // tokens for 4 s x 128 rows
    __shared__ unsigned short stage[2048];    // 16 rows x 128 bf16, swizzled

    tokL[tid] = x[(tid >> 2) * S_LEN + s0 + (tid & 3)];
    const int srow = tid >> 5, scol = tid & 31;
    __syncthreads();

    // depth-2 prefetch of embed rows (token index for tile mt is 16*mt + srow)
    f32x4 v0 = *(const f32x4*)(embed + (size_t)tokL[srow]      * 128 + scol * 4);
    f32x4 v1 = *(const f32x4*)(embed + (size_t)tokL[16 + srow] * 128 + scol * 4);

    for (int mt = 0; mt < 32; ++mt) {
        const int si = mt >> 3, bt16 = mt & 7;
        wg_barrier_lds();   // WAR: previous tile's A-reads done
        {
            unsigned short b4[4];
            b4[0]=f2bf(v0[0]); b4[1]=f2bf(v0[1]); b4[2]=f2bf(v0[2]); b4[3]=f2bf(v0[3]);
            int byte = srow * 256 + ((scol * 8) ^ ((srow & 7) << 4));
            *(uint2*)((char*)stage + byte) = *(const uint2*)b4;
        }
        wg_barrier_lds();   // RAW: stage ready
        // prefetch tile mt+2 (clamped at the tail; duplicate loads are harmless)
        const int mt2 = (mt < 30) ? (mt + 2) : mt;
        f32x4 v2 = *(const f32x4*)(embed + (size_t)tokL[16 * mt2 + srow] * 128 + scol * 4);

        bf16x8 A[4];
#pragma unroll
        for (int kt = 0; kt < 4; ++kt) {
            int byte = l15 * 256 + ((kt * 64 + l4 * 16) ^ ((l15 & 7) << 4));
            A[kt] = *(const bf16x8*)((const char*)stage + byte);
        }
        unsigned short ov[16];
#pragma unroll
        for (int q = 0; q < 4; ++q) {
            f32x4 acc = { bq[q], bq[q], bq[q], bq[q] };
#pragma unroll
            for (int kt = 0; kt < 4; ++kt)
                acc = __builtin_amdgcn_mfma_f32_16x16x32_bf16(A[kt], Bf[q][kt], acc, 0, 0, 0);
            ov[q*4+0]=f2bf(acc[0]); ov[q*4+1]=f2bf(acc[1]);
            ov[q*4+2]=f2bf(acc[2]); ov[q*4+3]=f2bf(acc[3]);
        }
        const int s = s0 + si;
        unsigned short* dst = xg +
            (((((size_t)s * 2 + dir) * 32 + bt16 * 4 + l4) * 8 + wv) * 256 + l15 * 16);
        *(u32x4*)dst       = *(const u32x4*)&ov[0];
        *(u32x4*)(dst + 8) = *(const u32x4*)&ov[8];
        v0 = v1; v1 = v2;
    }
}

// ---------------------------------------------------------------------------
// Kernel 2: LSTM recurrence, 64 WGs x 4 batch rows. A-rows & C-init duplicated
// (row l15&3) so every lane's acc[q][j] = gates for batch row j; select j=l4.
// h double-buffered in LDS with granule rotation. Emission MFMA multiplexed
// over waves by t&7. Raw barriers (lgkmcnt-only) + depth-2 xg prefetch keep
// the global xg loads in flight across steps.
// ---------------------------------------------------------------------------
__global__ __launch_bounds__(512) void k_lstm(
    const unsigned short* __restrict__ xg,
    const float* __restrict__ Whf, const float* __restrict__ Whb,
    const float* __restrict__ Wout, float* __restrict__ emp)
{
    const int dir = blockIdx.y, bt = blockIdx.x;       // bt: 0..31 (4-row tiles)
    const float* __restrict__ Wh = dir ? Whb : Whf;
    const int tid = threadIdx.x, w = tid >> 6, L = tid & 63, l15 = L & 15, l4 = L >> 4;

    bf16x8 Bf[4][4];
#pragma unroll
    for (int q = 0; q < 4; ++q)
#pragma unroll
        for (int kt = 0; kt < 4; ++kt)
            Bf[q][kt] = cvt8(Wh + (q * 128 + w * 16 + l15) * 128 + kt * 32 + l4 * 8);

    bf16x8 Of[4];
#pragma unroll
    for (int kt = 0; kt < 4; ++kt) { bf16x8 z;
#pragma unroll
        for (int i = 0; i < 8; ++i) z[i] = 0; Of[kt] = z; }
    if (l15 < NT) {
#pragma unroll
        for (int kt = 0; kt < 4; ++kt)
            Of[kt] = cvt8(Wout + l15 * 256 + dir * 128 + kt * 32 + l4 * 8);
    }

    __shared__ unsigned short hl[2048];   // 2 bufs x 4 rows x 256B, rotated granules
    for (int i = tid; i < 1024; i += 512) ((unsigned*)hl)[i] = 0;

    // A-read byte offsets (row = l15&3, granule rotation (g + 2*row)&15)
    const int ar = l15 & 3;
    int rdoff[4];
#pragma unroll
    for (int kt = 0; kt < 4; ++kt) {
        int p = (kt * 4 + l4 + 2 * ar) & 15;
        rdoff[kt] = ar * 256 + p * 16;
    }
    // h write offset: row=l4, col hc
    const int hc = w * 16 + l15;
    const int wroff = l4 * 256 + (((hc >> 3) + 2 * l4) & 15) * 16 + (hc & 7) * 2;

    float c = 0.f;
    const size_t xstep = (size_t)2 * 32 * 8 * 256;   // elements per s
    const size_t xbase = (((size_t)dir * 32 + bt) * 8 + w) * 256 + l15 * 16;

    // depth-2 prefetch pipeline: x0 = step t, x1 = t+1, x2 = t+2
    u16x16 x0 = *(const u16x16*)(xg + xbase + (size_t)(dir ? 511 : 510 + 1 - 1) * 0 + (size_t)(dir ? 511 : 0) * xstep);
    u16x16 x1 = *(const u16x16*)(xg + xbase + (size_t)(dir ? 510 : 1) * xstep);
    __syncthreads();   // covers hl zero-init (cold path, drain is fine)

    for (int t = 0; t < 512; ++t) {
        const char* bufR = (const char*)hl + (t & 1) * 1024;
        char*       bufW = (char*)hl + ((t & 1) ^ 1) * 1024;

        // issue prefetch for t+2 (clamped tail; duplicate loads are harmless)
        const int tc = (t < 510) ? (t + 2) : t;
        const int s2 = dir ? (511 - tc) : tc;
        u16x16 x2 = *(const u16x16*)(xg + xbase + (size_t)s2 * xstep);

        bf16x8 A[4];
#pragma unroll
        for (int kt = 0; kt < 4; ++kt)
            A[kt] = *(const bf16x8*)(bufR + rdoff[kt]);

        f32x4 acc[4];
#pragma unroll
        for (int q = 0; q < 4; ++q) {
            f32x4 a0 = { bf2f(x0[q*4+0]), bf2f(x0[q*4+1]), bf2f(x0[q*4+2]), bf2f(x0[q*4+3]) };
#pragma unroll
            for (int kt = 0; kt < 4; ++kt)
                a0 = __builtin_amdgcn_mfma_f32_16x16x32_bf16(A[kt], Bf[q][kt], a0, 0, 0, 0);
            acc[q] = a0;
        }
        // emission for position of h_{t-1}; wave (t&7) does it (A is wave-invariant)
        if (t > 0 && w == (t & 7)) {
            f32x4 em0 = {0, 0, 0, 0};
#pragma unroll
            for (int kt = 0; kt < 4; ++kt)
                em0 = __builtin_amdgcn_mfma_f32_16x16x32_bf16(A[kt], Of[kt], em0, 0, 0, 0);
            if (l4 == 0 && l15 < NT) {
                const int sp = dir ? (512 - t) : (t - 1);
#pragma unroll
                for (int j = 0; j < 4; ++j)
                    emp[((size_t)(dir * 128 + bt * 4 + j) * 512 + sp) * 9 + l15] = em0[j];
            }
        }
        // pointwise: one (row=l4, hc) pair per lane
        float ig = sigf(sel4(acc[0], l4));
        float fg = sigf(sel4(acc[1], l4));
        float gg = tanhf_(sel4(acc[2], l4));
        float og = sigf(sel4(acc[3], l4));
        c = fg * c + ig * gg;
        float h = og * tanhf_(c);
        *(unsigned short*)(bufW + wroff) = f2bf(h);
        wg_barrier_lds();          // LDS-only drain + barrier; vmem stays in flight
        x0 = x1; x1 = x2;
    }
    // final position emission (h from t=511 sits in buf 0)
    if (w == 0) {
        bf16x8 A[4];
#pragma unroll
        for (int kt = 0; kt < 4; ++kt)
            A[kt] = *(const bf16x8*)((const char*)hl + rdoff[kt]);
        f32x4 em0 = {0, 0, 0, 0};
#pragma unroll
        for (int kt = 0; kt < 4; ++kt)
            em0 = __builtin_amdgcn_mfma_f32_16x16x32_bf16(A[kt], Of[kt], em0, 0, 0, 0);
        if (l4 == 0 && l15 < NT) {
            const int sp = dir ? 0 : 511;
#pragma unroll
            for (int j = 0; j < 4; ++j)
                emp[((size_t)(dir * 128 + bt * 4 + j) * 512 + sp) * 9 + l15] = em0[j];
        }
    }
}

// ---------------------------------------------------------------------------
// Kernel 3: Viterbi. 256-thread staging; wave-0 forward DP with hoisted
// transitions; blocked backtrace (32 composition maps of 16 steps).
// ---------------------------------------------------------------------------
__global__ __launch_bounds__(256) void k_viterbi(
    const float* __restrict__ emp, const int* __restrict__ mask,
    const float* __restrict__ bout, const float* __restrict__ startt,
    const float* __restrict__ trans, const float* __restrict__ endt,
    float* __restrict__ out)
{
    const int b = blockIdx.x, tid = threadIdx.x;
    __shared__ float em[512 * 9];
    __shared__ int   msk[512];
    __shared__ unsigned char hist[512 * 9];
    __shared__ unsigned char Gl[32 * 12];
    __shared__ unsigned char bound[32];
    __shared__ int curS;

    const float* pf = emp + (size_t)b * 4608;
    const float* pb = emp + (size_t)(128 + b) * 4608;
    for (int i = tid; i < 4608; i += 256) {
        unsigned q = ((unsigned)i * 7282u) >> 16;          // i/9 for i<4608
        em[i] = pf[i] + pb[i] + bout[i - 9 * q];
    }
    for (int i = tid; i < 512; i += 256) msk[i] = mask[b * 512 + i];
    __syncthreads();

    if (tid < 64) {   // wave 0: forward DP
        const int k = (tid < NT) ? tid : 0;
        float trk[9];
#pragma unroll
        for (int j = 0; j < NT; ++j) trk[j] = trans[j * 9 + k];
        float score = startt[k] + em[k];
        for (int t = 1; t < 512; ++t) {
            float v[9];
#pragma unroll
            for (int j = 0; j < NT; ++j) v[j] = __shfl(score, j, 64) + trk[j];
            float m01 = fmaxf(v[0], v[1]), m23 = fmaxf(v[2], v[3]);
            float m45 = fmaxf(v[4], v[5]), m67 = fmaxf(v[6], v[7]);
            float m = fmaxf(fmaxf(fmaxf(m01, m23), fmaxf(m45, m67)), v[8]);
            int bi = 0;
#pragma unroll
            for (int j = 8; j >= 0; --j) if (v[j] == m) bi = j;   // first index
            if (msk[t]) score = m + em[t * 9 + k];
            if (tid < NT) hist[t * 9 + tid] = (unsigned char)bi;
        }
        float fin = score + endt[k];
        float bs = -3e38f; int cur = 0;
#pragma unroll
        for (int j = 0; j < NT; ++j) {
            float vv = __shfl(fin, j, 64);
            if (vv > bs) { bs = vv; cur = j; }
        }
        if (tid == 0) { curS = cur; out[65536 + b] = bs; }
    }
    __syncthreads();

    // block composition maps: block m covers t in [16m+1, min(16m+16,511)]
    if (tid < 32) {
        const int m = tid;
        int G[9];
#pragma unroll
        for (int k = 0; k < NT; ++k) G[k] = k;
        const int hi = (m == 31) ? 511 : (16 * m + 16);
        for (int t = hi; t >= 16 * m + 1; --t) {
            if (msk[t]) {
#pragma unroll
                for (int k = 0; k < NT; ++k) G[k] = hist[t * 9 + G[k]];
            }
        }
#pragma unroll
        for (int k = 0; k < NT; ++k) Gl[m * 12 + k] = (unsigned char)G[k];
    }
    __syncthreads();

    if (tid == 0) {   // serial boundary walk (31 steps)
        int e = curS;
        bound[31] = (unsigned char)e;
        for (int m = 31; m >= 1; --m) { e = Gl[m * 12 + e]; bound[m - 1] = (unsigned char)e; }
        out[(size_t)b * 512] = (float)Gl[0 * 12 + e];   // c_0
    }
    __syncthreads();

    if (tid < 32) {   // lane-parallel interior backtrace
        const int m = tid;
        int ccur = bound[m];
        const int hi = (m == 31) ? 511 : (16 * m + 16);
        for (int t = hi; t >= 16 * m + 1; --t) {
            const int mt = msk[t];
            out[(size_t)b * 512 + t] = (float)(mt ? ccur : -1);
            if (mt) ccur = hist[t * 9 + ccur];
        }
    }
}

// ---------------------------------------------------------------------------
extern "C" void kernel_launch(void* const* d_in, const int* in_sizes, int n_in,
                              void* d_out, int out_size, void* d_ws, size_t ws_size,
                              hipStream_t stream) {
    const int*   x      = (const int*)d_in[0];
    const int*   mask   = (const int*)d_in[1];
    const float* embed  = (const float*)d_in[2];
    const float* Wihf   = (const float*)d_in[3];
    const float* Whhf   = (const float*)d_in[4];
    const float* bf_    = (const float*)d_in[5];
    const float* Wihb   = (const float*)d_in[6];
    const float* Whhb   = (const float*)d_in[7];
    const float* bb_    = (const float*)d_in[8];
    const float* Wout   = (const float*)d_in[9];
    const float* bout   = (const float*)d_in[10];
    const float* startt = (const float*)d_in[11];
    const float* trans  = (const float*)d_in[12];
    const float* endt   = (const float*)d_in[13];

    unsigned short* xg  = (unsigned short*)d_ws;                       // 128 MB bf16
    float*          emp = (float*)((char*)d_ws + (size_t)134217728);   // 4.5 MB f32
    float*          out = (float*)d_out;

    k_xg     <<<dim3(128, 2), 512, 0, stream>>>(x, embed, Wihf, bf_, Wihb, bb_, xg);
    k_lstm   <<<dim3(32, 2),  512, 0, stream>>>(xg, Whhf, Whhb, Wout, emp);
    k_viterbi<<<128,          256, 0, stream>>>(emp, mask, bout, startt, trans, endt, out);
}

// Round 4
// 462.725 us; speedup vs baseline: 1.0702x; 1.0702x over previous
//
#include <hip/hip_runtime.h>
#include <stdint.h>

#define S_LEN 512
#define NT 9

typedef __attribute__((ext_vector_type(8)))  short          bf16x8;
typedef __attribute__((ext_vector_type(4)))  float          f32x4;
typedef __attribute__((ext_vector_type(16))) unsigned short u16x16;
typedef __attribute__((ext_vector_type(4)))  unsigned int   u32x4;

static __device__ __forceinline__ unsigned short f2bf(float f) {
    union { float f; unsigned u; } c; c.f = f;
    return (unsigned short)((c.u + 0x7fffu + ((c.u >> 16) & 1u)) >> 16); // RNE
}
static __device__ __forceinline__ float bf2f(unsigned short h) {
    union { unsigned u; float f; } c; c.u = ((unsigned)h) << 16;
    return c.f;
}
static __device__ __forceinline__ bf16x8 cvt8(const float* p) {
    f32x4 a = *(const f32x4*)p, b = *(const f32x4*)(p + 4);
    bf16x8 fr;
    fr[0]=(short)f2bf(a[0]); fr[1]=(short)f2bf(a[1]); fr[2]=(short)f2bf(a[2]); fr[3]=(short)f2bf(a[3]);
    fr[4]=(short)f2bf(b[0]); fr[5]=(short)f2bf(b[1]); fr[6]=(short)f2bf(b[2]); fr[7]=(short)f2bf(b[3]);
    return fr;
}
static __device__ __forceinline__ float sigf(float x) {
    return __builtin_amdgcn_rcpf(1.0f + __expf(-x));
}
static __device__ __forceinline__ float tanhf_(float x) {
    return 1.0f - 2.0f * __builtin_amdgcn_rcpf(1.0f + __expf(2.0f * x));
}
static __device__ __forceinline__ float sel4(f32x4 a, int l4) {
    float x01 = (l4 & 1) ? a[1] : a[0];
    float x23 = (l4 & 1) ? a[3] : a[2];
    return (l4 & 2) ? x23 : x01;
}

// Raw workgroup barrier that waits ONLY LDS ops (lgkmcnt) — global loads and
// stores stay in flight across it.
static __device__ __forceinline__ void wg_barrier_lds() {
    asm volatile("s_waitcnt lgkmcnt(0)" ::: "memory");
    __builtin_amdgcn_s_barrier();
    asm volatile("" ::: "memory");
}

// ---------------------------------------------------------------------------
// Kernel 1: xg = emb[x] @ W_ih^T + b, bf16, layout consumed by k_lstm:
//   element(s, dir, b, gate{q,w,l15}) at
//   ((((s*2+dir)*32 + (b>>2))*8 + w)*256 + l15*16 + q*4 + (b&3))
// One WG per (s, dir): 128 tokens staged, 8 tiles of 16 batch rows.
// ---------------------------------------------------------------------------
__global__ __launch_bounds__(512) void k_xg(
    const int* __restrict__ x, const float* __restrict__ embed,
    const float* __restrict__ Wf, const float* __restrict__ bF,
    const float* __restrict__ Wb, const float* __restrict__ bB,
    unsigned short* __restrict__ xg)
{
    const int dir = blockIdx.y, s = blockIdx.x;
    const float* __restrict__ W    = dir ? Wb : Wf;
    const float* __restrict__ bias = dir ? bB : bF;
    const int tid = threadIdx.x;
    const int wv = tid >> 6, L = tid & 63, l15 = L & 15, l4 = L >> 4;

    // W_ih B-fragments in registers (64 VGPR)
    bf16x8 Bf[4][4];
    float  bq[4];
#pragma unroll
    for (int q = 0; q < 4; ++q) {
        const int gate = q * 128 + wv * 16 + l15;
        bq[q] = bias[gate];
#pragma unroll
        for (int kt = 0; kt < 4; ++kt)
            Bf[q][kt] = cvt8(W + gate * 128 + kt * 32 + l4 * 8);
    }

    __shared__ int tokL[128];                 // tokens: rows 0..127 at this s
    __shared__ unsigned short stage[2048];    // 16 rows x 128 bf16, swizzled

    if (tid < 128) tokL[tid] = x[tid * S_LEN + s];
    const int srow = tid >> 5, scol = tid & 31;
    __syncthreads();

    // depth-2 prefetch: tile bt16 stages rows bt16*16 + srow
    f32x4 v0 = *(const f32x4*)(embed + (size_t)tokL[srow]      * 128 + scol * 4);
    f32x4 v1 = *(const f32x4*)(embed + (size_t)tokL[16 + srow] * 128 + scol * 4);

    for (int bt16 = 0; bt16 < 8; ++bt16) {
        wg_barrier_lds();   // WAR: previous tile's A-reads done
        {
            unsigned short b4[4];
            b4[0]=f2bf(v0[0]); b4[1]=f2bf(v0[1]); b4[2]=f2bf(v0[2]); b4[3]=f2bf(v0[3]);
            int byte = srow * 256 + ((scol * 8) ^ ((srow & 7) << 4));
            *(uint2*)((char*)stage + byte) = *(const uint2*)b4;
        }
        wg_barrier_lds();   // RAW: stage ready
        const int nt2 = (bt16 < 6) ? (bt16 + 2) : bt16;   // clamped prefetch
        f32x4 v2 = *(const f32x4*)(embed + (size_t)tokL[nt2 * 16 + srow] * 128 + scol * 4);

        bf16x8 A[4];
#pragma unroll
        for (int kt = 0; kt < 4; ++kt) {
            int byte = l15 * 256 + ((kt * 64 + l4 * 16) ^ ((l15 & 7) << 4));
            A[kt] = *(const bf16x8*)((const char*)stage + byte);
        }
        unsigned short ov[16];
#pragma unroll
        for (int q = 0; q < 4; ++q) {
            f32x4 acc = { bq[q], bq[q], bq[q], bq[q] };
#pragma unroll
            for (int kt = 0; kt < 4; ++kt)
                acc = __builtin_amdgcn_mfma_f32_16x16x32_bf16(A[kt], Bf[q][kt], acc, 0, 0, 0);
            ov[q*4+0]=f2bf(acc[0]); ov[q*4+1]=f2bf(acc[1]);
            ov[q*4+2]=f2bf(acc[2]); ov[q*4+3]=f2bf(acc[3]);
        }
        // D row r = l4*4+j = batch row bt16*16 + 4*l4 + j  ->  B4 = bt16*4+l4, elem j
        unsigned short* dst = xg +
            (((((size_t)s * 2 + dir) * 32 + bt16 * 4 + l4) * 8 + wv) * 256 + l15 * 16);
        *(u32x4*)dst       = *(const u32x4*)&ov[0];
        *(u32x4*)(dst + 8) = *(const u32x4*)&ov[8];
        v0 = v1; v1 = v2;
    }
}

// ---------------------------------------------------------------------------
// Kernel 2: LSTM recurrence only (emissions moved out). 64 WGs x 4 batch rows.
// A-rows & C-init duplicated (row l15&3); lane selects j=l4. h double-buffered
// in LDS with granule rotation. h also streamed to feats (bf16, fire-and-
// forget; the lgkmcnt-only barrier never waits on it).
// ---------------------------------------------------------------------------
__global__ __launch_bounds__(512) void k_lstm(
    const unsigned short* __restrict__ xg,
    const float* __restrict__ Whf, const float* __restrict__ Whb,
    unsigned short* __restrict__ feats)
{
    const int dir = blockIdx.y, bt = blockIdx.x;       // bt: 0..31 (4-row tiles)
    const float* __restrict__ Wh = dir ? Whb : Whf;
    const int tid = threadIdx.x, w = tid >> 6, L = tid & 63, l15 = L & 15, l4 = L >> 4;

    bf16x8 Bf[4][4];
#pragma unroll
    for (int q = 0; q < 4; ++q)
#pragma unroll
        for (int kt = 0; kt < 4; ++kt)
            Bf[q][kt] = cvt8(Wh + (q * 128 + w * 16 + l15) * 128 + kt * 32 + l4 * 8);

    __shared__ unsigned short hl[2048];   // 2 bufs x 4 rows x 256B, rotated granules
    for (int i = tid; i < 1024; i += 512) ((unsigned*)hl)[i] = 0;

    // A-read byte offsets (row = l15&3, granule rotation (g + 2*row)&15)
    const int ar = l15 & 3;
    int rdoff[4];
#pragma unroll
    for (int kt = 0; kt < 4; ++kt) {
        int p = (kt * 4 + l4 + 2 * ar) & 15;
        rdoff[kt] = ar * 256 + p * 16;
    }
    // h write offset: row=l4, col hc
    const int hc = w * 16 + l15;
    const int wroff = l4 * 256 + (((hc >> 3) + 2 * l4) & 15) * 16 + (hc & 7) * 2;

    float c = 0.f;
    const size_t xstep = (size_t)2 * 32 * 8 * 256;   // elements per s
    const size_t xbase = (((size_t)dir * 32 + bt) * 8 + w) * 256 + l15 * 16;
    // feats base for this lane: row bt*4+l4, col dir*128+hc
    unsigned short* fptr = feats + ((size_t)(bt * 4 + l4) * 512) * 256 + dir * 128 + hc;

    u16x16 x0 = *(const u16x16*)(xg + xbase + (size_t)(dir ? 511 : 0) * xstep);
    u16x16 x1 = *(const u16x16*)(xg + xbase + (size_t)(dir ? 510 : 1) * xstep);
    __syncthreads();   // covers hl zero-init

    for (int t = 0; t < 512; ++t) {
        const char* bufR = (const char*)hl + (t & 1) * 1024;
        char*       bufW = (char*)hl + ((t & 1) ^ 1) * 1024;

        const int tc = (t < 510) ? (t + 2) : t;
        const int s2 = dir ? (511 - tc) : tc;
        u16x16 x2 = *(const u16x16*)(xg + xbase + (size_t)s2 * xstep);

        bf16x8 A[4];
#pragma unroll
        for (int kt = 0; kt < 4; ++kt)
            A[kt] = *(const bf16x8*)(bufR + rdoff[kt]);

        f32x4 acc[4];
#pragma unroll
        for (int q = 0; q < 4; ++q) {
            f32x4 a0 = { bf2f(x0[q*4+0]), bf2f(x0[q*4+1]), bf2f(x0[q*4+2]), bf2f(x0[q*4+3]) };
#pragma unroll
            for (int kt = 0; kt < 4; ++kt)
                a0 = __builtin_amdgcn_mfma_f32_16x16x32_bf16(A[kt], Bf[q][kt], a0, 0, 0, 0);
            acc[q] = a0;
        }
        // pointwise: one (row=l4, col=hc) pair per lane
        float ig = sigf(sel4(acc[0], l4));
        float fg = sigf(sel4(acc[1], l4));
        float gg = tanhf_(sel4(acc[2], l4));
        float og = sigf(sel4(acc[3], l4));
        c = fg * c + ig * gg;
        float h = og * tanhf_(c);
        unsigned short hb = f2bf(h);
        *(unsigned short*)(bufW + wroff) = hb;
        // stream h to feats (global, fire-and-forget)
        const int s_pos = dir ? (511 - t) : t;
        fptr[(size_t)s_pos * 256] = hb;
        wg_barrier_lds();          // LDS-only drain + barrier; vmem stays in flight
        x0 = x1; x1 = x2;
    }
}

// ---------------------------------------------------------------------------
// Kernel 2b: emissions from feats. One wave per (b, 16-step group); per dir a
// 4-MFMA zero-init chain (bit-identical to the former in-loop emission).
// ---------------------------------------------------------------------------
__global__ __launch_bounds__(256) void k_emis(
    const unsigned short* __restrict__ feats,
    const float* __restrict__ Wout, float* __restrict__ emp)
{
    const int tid = threadIdx.x;
    const int wid = blockIdx.x * 4 + (tid >> 6);
    const int L = tid & 63, l15 = L & 15, l4 = L >> 4;
    const int b = wid >> 5, sg = wid & 31;

    bf16x8 Of[2][4];
#pragma unroll
    for (int d = 0; d < 2; ++d)
#pragma unroll
        for (int kt = 0; kt < 4; ++kt) { bf16x8 z;
#pragma unroll
            for (int i = 0; i < 8; ++i) z[i] = 0; Of[d][kt] = z; }
    if (l15 < NT) {
#pragma unroll
        for (int d = 0; d < 2; ++d)
#pragma unroll
            for (int kt = 0; kt < 4; ++kt)
                Of[d][kt] = cvt8(Wout + l15 * 256 + d * 128 + kt * 32 + l4 * 8);
    }

    // A row r = feats row (b, s = sg*16 + r); lane l15 supplies row l15
    const unsigned short* frow = feats + ((size_t)b * 512 + sg * 16 + l15) * 256;
#pragma unroll
    for (int d = 0; d < 2; ++d) {
        bf16x8 A[4];
#pragma unroll
        for (int kt = 0; kt < 4; ++kt)
            A[kt] = *(const bf16x8*)(frow + d * 128 + kt * 32 + l4 * 8);
        f32x4 em0 = {0, 0, 0, 0};
#pragma unroll
        for (int kt = 0; kt < 4; ++kt)
            em0 = __builtin_amdgcn_mfma_f32_16x16x32_bf16(A[kt], Of[d][kt], em0, 0, 0, 0);
        if (l15 < NT) {
#pragma unroll
            for (int j = 0; j < 4; ++j)
                emp[((size_t)(d * 128 + b) * 512 + sg * 16 + l4 * 4 + j) * 9 + l15] = em0[j];
        }
    }
}

// ---------------------------------------------------------------------------
// Kernel 3: Viterbi (unchanged).
// ---------------------------------------------------------------------------
__global__ __launch_bounds__(256) void k_viterbi(
    const float* __restrict__ emp, const int* __restrict__ mask,
    const float* __restrict__ bout, const float* __restrict__ startt,
    const float* __restrict__ trans, const float* __restrict__ endt,
    float* __restrict__ out)
{
    const int b = blockIdx.x, tid = threadIdx.x;
    __shared__ float em[512 * 9];
    __shared__ int   msk[512];
    __shared__ unsigned char hist[512 * 9];
    __shared__ unsigned char Gl[32 * 12];
    __shared__ unsigned char bound[32];
    __shared__ int curS;

    const float* pf = emp + (size_t)b * 4608;
    const float* pb = emp + (size_t)(128 + b) * 4608;
    for (int i = tid; i < 4608; i += 256) {
        unsigned q = ((unsigned)i * 7282u) >> 16;          // i/9 for i<4608
        em[i] = pf[i] + pb[i] + bout[i - 9 * q];
    }
    for (int i = tid; i < 512; i += 256) msk[i] = mask[b * 512 + i];
    __syncthreads();

    if (tid < 64) {   // wave 0: forward DP
        const int k = (tid < NT) ? tid : 0;
        float trk[9];
#pragma unroll
        for (int j = 0; j < NT; ++j) trk[j] = trans[j * 9 + k];
        float score = startt[k] + em[k];
        for (int t = 1; t < 512; ++t) {
            float v[9];
#pragma unroll
            for (int j = 0; j < NT; ++j) v[j] = __shfl(score, j, 64) + trk[j];
            float m01 = fmaxf(v[0], v[1]), m23 = fmaxf(v[2], v[3]);
            float m45 = fmaxf(v[4], v[5]), m67 = fmaxf(v[6], v[7]);
            float m = fmaxf(fmaxf(fmaxf(m01, m23), fmaxf(m45, m67)), v[8]);
            int bi = 0;
#pragma unroll
            for (int j = 8; j >= 0; --j) if (v[j] == m) bi = j;   // first index
            if (msk[t]) score = m + em[t * 9 + k];
            if (tid < NT) hist[t * 9 + tid] = (unsigned char)bi;
        }
        float fin = score + endt[k];
        float bs = -3e38f; int cur = 0;
#pragma unroll
        for (int j = 0; j < NT; ++j) {
            float vv = __shfl(fin, j, 64);
            if (vv > bs) { bs = vv; cur = j; }
        }
        if (tid == 0) { curS = cur; out[65536 + b] = bs; }
    }
    __syncthreads();

    // block composition maps: block m covers t in [16m+1, min(16m+16,511)]
    if (tid < 32) {
        const int m = tid;
        int G[9];
#pragma unroll
        for (int k = 0; k < NT; ++k) G[k] = k;
        const int hi = (m == 31) ? 511 : (16 * m + 16);
        for (int t = hi; t >= 16 * m + 1; --t) {
            if (msk[t]) {
#pragma unroll
                for (int k = 0; k < NT; ++k) G[k] = hist[t * 9 + G[k]];
            }
        }
#pragma unroll
        for (int k = 0; k < NT; ++k) Gl[m * 12 + k] = (unsigned char)G[k];
    }
    __syncthreads();

    if (tid == 0) {   // serial boundary walk (31 steps)
        int e = curS;
        bound[31] = (unsigned char)e;
        for (int m = 31; m >= 1; --m) { e = Gl[m * 12 + e]; bound[m - 1] = (unsigned char)e; }
        out[(size_t)b * 512] = (float)Gl[0 * 12 + e];   // c_0
    }
    __syncthreads();

    if (tid < 32) {   // lane-parallel interior backtrace
        const int m = tid;
        int ccur = bound[m];
        const int hi = (m == 31) ? 511 : (16 * m + 16);
        for (int t = hi; t >= 16 * m + 1; --t) {
            const int mt = msk[t];
            out[(size_t)b * 512 + t] = (float)(mt ? ccur : -1);
            if (mt) ccur = hist[t * 9 + ccur];
        }
    }
}

// ---------------------------------------------------------------------------
extern "C" void kernel_launch(void* const* d_in, const int* in_sizes, int n_in,
                              void* d_out, int out_size, void* d_ws, size_t ws_size,
                              hipStream_t stream) {
    const int*   x      = (const int*)d_in[0];
    const int*   mask   = (const int*)d_in[1];
    const float* embed  = (const float*)d_in[2];
    const float* Wihf   = (const float*)d_in[3];
    const float* Whhf   = (const float*)d_in[4];
    const float* bf_    = (const float*)d_in[5];
    const float* Wihb   = (const float*)d_in[6];
    const float* Whhb   = (const float*)d_in[7];
    const float* bb_    = (const float*)d_in[8];
    const float* Wout   = (const float*)d_in[9];
    const float* bout   = (const float*)d_in[10];
    const float* startt = (const float*)d_in[11];
    const float* trans  = (const float*)d_in[12];
    const float* endt   = (const float*)d_in[13];

    unsigned short* xg    = (unsigned short*)d_ws;                        // 128 MB bf16
    float*          emp   = (float*)((char*)d_ws + (size_t)134217728);    // 4.5 MB f32
    unsigned short* feats = (unsigned short*)((char*)d_ws + (size_t)138936320); // 32 MB bf16
    float*          out   = (float*)d_out;

    k_xg     <<<dim3(512, 2), 512, 0, stream>>>(x, embed, Wihf, bf_, Wihb, bb_, xg);
    k_lstm   <<<dim3(32, 2),  512, 0, stream>>>(xg, Whhf, Whhb, feats);
    k_emis   <<<1024,         256, 0, stream>>>(feats, Wout, emp);
    k_viterbi<<<128,          256, 0, stream>>>(emp, mask, bout, startt, trans, endt, out);
}

// Round 5
// 407.613 us; speedup vs baseline: 1.2149x; 1.1352x over previous
//
#include <hip/hip_runtime.h>
#include <stdint.h>

#define S_LEN 512
#define NT 9

typedef __attribute__((ext_vector_type(8)))  short          bf16x8;
typedef __attribute__((ext_vector_type(4)))  float          f32x4;
typedef __attribute__((ext_vector_type(4)))  unsigned short u16x4;
typedef __attribute__((ext_vector_type(4)))  unsigned int   u32x4;

static __device__ __forceinline__ unsigned short f2bf(float f) {
    union { float f; unsigned u; } c; c.f = f;
    return (unsigned short)((c.u + 0x7fffu + ((c.u >> 16) & 1u)) >> 16); // RNE
}
static __device__ __forceinline__ float bf2f(unsigned short h) {
    union { unsigned u; float f; } c; c.u = ((unsigned)h) << 16;
    return c.f;
}
static __device__ __forceinline__ bf16x8 cvt8(const float* p) {
    f32x4 a = *(const f32x4*)p, b = *(const f32x4*)(p + 4);
    bf16x8 fr;
    fr[0]=(short)f2bf(a[0]); fr[1]=(short)f2bf(a[1]); fr[2]=(short)f2bf(a[2]); fr[3]=(short)f2bf(a[3]);
    fr[4]=(short)f2bf(b[0]); fr[5]=(short)f2bf(b[1]); fr[6]=(short)f2bf(b[2]); fr[7]=(short)f2bf(b[3]);
    return fr;
}
static __device__ __forceinline__ float sigf(float x) {
    return __builtin_amdgcn_rcpf(1.0f + __expf(-x));
}
static __device__ __forceinline__ float tanhf_(float x) {
    return 1.0f - 2.0f * __builtin_amdgcn_rcpf(1.0f + __expf(2.0f * x));
}

// Raw workgroup barrier that waits ONLY LDS ops (lgkmcnt) — global loads and
// stores stay in flight across it.
static __device__ __forceinline__ void wg_barrier_lds() {
    asm volatile("s_waitcnt lgkmcnt(0)" ::: "memory");
    __builtin_amdgcn_s_barrier();
    asm volatile("" ::: "memory");
}

// ---------------------------------------------------------------------------
// Kernel 1: xg = emb[x] @ W_ih^T + b, bf16, NEW layout (q-contiguous per col):
//   element(s, dir, b, gate = q*128 + hc) at
//   ((s*2+dir)*128 + b)*512 + hc*4 + q      (hc = w*16+l15 in k_lstm terms)
// One WG per (s, dir). MFMA math identical to R4 (bit-identical xg values).
// ---------------------------------------------------------------------------
__global__ __launch_bounds__(512) void k_xg(
    const int* __restrict__ x, const float* __restrict__ embed,
    const float* __restrict__ Wf, const float* __restrict__ bF,
    const float* __restrict__ Wb, const float* __restrict__ bB,
    unsigned short* __restrict__ xg)
{
    const int dir = blockIdx.y, s = blockIdx.x;
    const float* __restrict__ W    = dir ? Wb : Wf;
    const float* __restrict__ bias = dir ? bB : bF;
    const int tid = threadIdx.x;
    const int wv = tid >> 6, L = tid & 63, l15 = L & 15, l4 = L >> 4;

    // W_ih B-fragments in registers (64 VGPR)
    bf16x8 Bf[4][4];
    float  bq[4];
#pragma unroll
    for (int q = 0; q < 4; ++q) {
        const int gate = q * 128 + wv * 16 + l15;
        bq[q] = bias[gate];
#pragma unroll
        for (int kt = 0; kt < 4; ++kt)
            Bf[q][kt] = cvt8(W + gate * 128 + kt * 32 + l4 * 8);
    }

    __shared__ int tokL[128];                 // tokens: rows 0..127 at this s
    __shared__ unsigned short stage[2048];    // 16 rows x 128 bf16, swizzled

    if (tid < 128) tokL[tid] = x[tid * S_LEN + s];
    const int srow = tid >> 5, scol = tid & 31;
    __syncthreads();

    // depth-2 prefetch: tile bt16 stages rows bt16*16 + srow
    f32x4 v0 = *(const f32x4*)(embed + (size_t)tokL[srow]      * 128 + scol * 4);
    f32x4 v1 = *(const f32x4*)(embed + (size_t)tokL[16 + srow] * 128 + scol * 4);

    const int hc = wv * 16 + l15;

    for (int bt16 = 0; bt16 < 8; ++bt16) {
        wg_barrier_lds();   // WAR: previous tile's A-reads done
        {
            unsigned short b4[4];
            b4[0]=f2bf(v0[0]); b4[1]=f2bf(v0[1]); b4[2]=f2bf(v0[2]); b4[3]=f2bf(v0[3]);
            int byte = srow * 256 + ((scol * 8) ^ ((srow & 7) << 4));
            *(uint2*)((char*)stage + byte) = *(const uint2*)b4;
        }
        wg_barrier_lds();   // RAW: stage ready
        const int nt2 = (bt16 < 6) ? (bt16 + 2) : bt16;   // clamped prefetch
        f32x4 v2 = *(const f32x4*)(embed + (size_t)tokL[nt2 * 16 + srow] * 128 + scol * 4);

        bf16x8 A[4];
#pragma unroll
        for (int kt = 0; kt < 4; ++kt) {
            int byte = l15 * 256 + ((kt * 64 + l4 * 16) ^ ((l15 & 7) << 4));
            A[kt] = *(const bf16x8*)((const char*)stage + byte);
        }
        f32x4 acc[4];
#pragma unroll
        for (int q = 0; q < 4; ++q) {
            f32x4 a0 = { bq[q], bq[q], bq[q], bq[q] };
#pragma unroll
            for (int kt = 0; kt < 4; ++kt)
                a0 = __builtin_amdgcn_mfma_f32_16x16x32_bf16(A[kt], Bf[q][kt], a0, 0, 0, 0);
            acc[q] = a0;
        }
        // D row r = l4*4+j = batch row bt16*16 + l4*4 + j; store [b][hc][q] bf16
#pragma unroll
        for (int j = 0; j < 4; ++j) {
            u16x4 sv;
#pragma unroll
            for (int q = 0; q < 4; ++q) sv[q] = f2bf(acc[q][j]);
            unsigned short* dst = xg +
                (((size_t)s * 2 + dir) * 128 + bt16 * 16 + l4 * 4 + j) * 512 + hc * 4;
            *(u16x4*)dst = sv;
        }
        v0 = v1; v1 = v2;
    }
}

// ---------------------------------------------------------------------------
// Kernel 2: LSTM recurrence. 64 WGs x 4 batch rows. A-row r carries h[r>>2]
// so ALL 4 D-elements of a lane equal row l4 (no select); C-init only needs
// element 0 (acc[q][1..3] accumulate bounded garbage, never read). 8B xg
// loads, 2x unrolled loop, lgkmcnt-only barrier, 1 barrier/step.
// ---------------------------------------------------------------------------
__global__ __launch_bounds__(512) void k_lstm(
    const unsigned short* __restrict__ xg,
    const float* __restrict__ Whf, const float* __restrict__ Whb,
    unsigned short* __restrict__ feats)
{
    const int dir = blockIdx.y, bt = blockIdx.x;       // bt: 0..31 (4-row tiles)
    const float* __restrict__ Wh = dir ? Whb : Whf;
    const int tid = threadIdx.x, w = tid >> 6, L = tid & 63, l15 = L & 15, l4 = L >> 4;

    bf16x8 Bf[4][4];
#pragma unroll
    for (int q = 0; q < 4; ++q)
#pragma unroll
        for (int kt = 0; kt < 4; ++kt)
            Bf[q][kt] = cvt8(Wh + (q * 128 + w * 16 + l15) * 128 + kt * 32 + l4 * 8);

    __shared__ unsigned short hl[2048];   // 2 bufs x 4 rows x 256B, rotated granules
    for (int i = tid; i < 1024; i += 512) ((unsigned*)hl)[i] = 0;

    // A-read byte offsets: A row r = l15 carries h[l15>>2]; slice kt*32+l4*8.
    const int ar = l15 >> 2;
    int rdoff[4];
#pragma unroll
    for (int kt = 0; kt < 4; ++kt) {
        int p = (kt * 4 + l4 + 2 * ar) & 15;
        rdoff[kt] = ar * 256 + p * 16;
    }
    // h write offset: row=l4, col hc (same rotation family as reads)
    const int hc = w * 16 + l15;
    const int wroff = l4 * 256 + (((hc >> 3) + 2 * l4) & 15) * 16 + (hc & 7) * 2;

    float c = 0.f;
    // xg addressing: ((s*2+dir)*128 + bt*4 + l4)*512 + hc*4, ushort4 loads
    const size_t xoff = ((size_t)(bt * 4 + l4)) * 512 + hc * 4;
    const unsigned short* xp = xg + xoff + (size_t)dir * 65536;
    // feats: row bt*4+l4, col dir*128+hc
    unsigned short* fcur = feats + ((size_t)(bt * 4 + l4) * 512 + (dir ? 511 : 0)) * 256
                                 + dir * 128 + hc;
    const ptrdiff_t fstep = dir ? -256 : 256;

    u16x4 xvA = *(const u16x4*)(xp + (size_t)(dir ? 511 : 0) * 131072);
    u16x4 xvB = *(const u16x4*)(xp + (size_t)(dir ? 510 : 1) * 131072);

    f32x4 acc[4];
#pragma unroll
    for (int q = 0; q < 4; ++q) acc[q] = f32x4{0.f, 0.f, 0.f, 0.f};

    __syncthreads();   // covers hl zero-init

#define LSTM_STEP(T, XV)                                                        \
    {                                                                           \
        const int t_ = (T);                                                     \
        const char* bufR = (const char*)hl + (t_ & 1) * 1024;                   \
        char*       bufW = (char*)hl + ((t_ & 1) ^ 1) * 1024;                   \
        const int tc_ = (t_ < 510) ? (t_ + 2) : t_;                             \
        const int s2_ = dir ? (511 - tc_) : tc_;                                \
        u16x4 xnew = *(const u16x4*)(xp + (size_t)s2_ * 131072);                \
        bf16x8 A_[4];                                                           \
        _Pragma("unroll")                                                       \
        for (int kt = 0; kt < 4; ++kt)                                          \
            A_[kt] = *(const bf16x8*)(bufR + rdoff[kt]);                        \
        _Pragma("unroll")                                                       \
        for (int q = 0; q < 4; ++q) {                                           \
            acc[q][0] = bf2f(XV[q]);                                            \
            _Pragma("unroll")                                                   \
            for (int kt = 0; kt < 4; ++kt)                                      \
                acc[q] = __builtin_amdgcn_mfma_f32_16x16x32_bf16(               \
                             A_[kt], Bf[q][kt], acc[q], 0, 0, 0);               \
        }                                                                       \
        float ig = sigf(acc[0][0]);                                             \
        float fg = sigf(acc[1][0]);                                             \
        float gg = tanhf_(acc[2][0]);                                           \
        float og = sigf(acc[3][0]);                                             \
        c = fg * c + ig * gg;                                                   \
        float h_ = og * tanhf_(c);                                              \
        unsigned short hb = f2bf(h_);                                           \
        *(unsigned short*)(bufW + wroff) = hb;                                  \
        *fcur = hb; fcur += fstep;                                              \
        wg_barrier_lds();                                                       \
        XV = xnew;                                                              \
    }

    for (int it = 0; it < 256; ++it) {
        LSTM_STEP(2 * it,     xvA)
        LSTM_STEP(2 * it + 1, xvB)
    }
#undef LSTM_STEP
}

// ---------------------------------------------------------------------------
// Kernel 2b: emissions from feats (unchanged).
// ---------------------------------------------------------------------------
__global__ __launch_bounds__(256) void k_emis(
    const unsigned short* __restrict__ feats,
    const float* __restrict__ Wout, float* __restrict__ emp)
{
    const int tid = threadIdx.x;
    const int wid = blockIdx.x * 4 + (tid >> 6);
    const int L = tid & 63, l15 = L & 15, l4 = L >> 4;
    const int b = wid >> 5, sg = wid & 31;

    bf16x8 Of[2][4];
#pragma unroll
    for (int d = 0; d < 2; ++d)
#pragma unroll
        for (int kt = 0; kt < 4; ++kt) { bf16x8 z;
#pragma unroll
            for (int i = 0; i < 8; ++i) z[i] = 0; Of[d][kt] = z; }
    if (l15 < NT) {
#pragma unroll
        for (int d = 0; d < 2; ++d)
#pragma unroll
            for (int kt = 0; kt < 4; ++kt)
                Of[d][kt] = cvt8(Wout + l15 * 256 + d * 128 + kt * 32 + l4 * 8);
    }

    const unsigned short* frow = feats + ((size_t)b * 512 + sg * 16 + l15) * 256;
#pragma unroll
    for (int d = 0; d < 2; ++d) {
        bf16x8 A[4];
#pragma unroll
        for (int kt = 0; kt < 4; ++kt)
            A[kt] = *(const bf16x8*)(frow + d * 128 + kt * 32 + l4 * 8);
        f32x4 em0 = {0, 0, 0, 0};
#pragma unroll
        for (int kt = 0; kt < 4; ++kt)
            em0 = __builtin_amdgcn_mfma_f32_16x16x32_bf16(A[kt], Of[d][kt], em0, 0, 0, 0);
        if (l15 < NT) {
#pragma unroll
            for (int j = 0; j < 4; ++j)
                emp[((size_t)(d * 128 + b) * 512 + sg * 16 + l4 * 4 + j) * 9 + l15] = em0[j];
        }
    }
}

// ---------------------------------------------------------------------------
// Kernel 3: Viterbi (unchanged).
// ---------------------------------------------------------------------------
__global__ __launch_bounds__(256) void k_viterbi(
    const float* __restrict__ emp, const int* __restrict__ mask,
    const float* __restrict__ bout, const float* __restrict__ startt,
    const float* __restrict__ trans, const float* __restrict__ endt,
    float* __restrict__ out)
{
    const int b = blockIdx.x, tid = threadIdx.x;
    __shared__ float em[512 * 9];
    __shared__ int   msk[512];
    __shared__ unsigned char hist[512 * 9];
    __shared__ unsigned char Gl[32 * 12];
    __shared__ unsigned char bound[32];
    __shared__ int curS;

    const float* pf = emp + (size_t)b * 4608;
    const float* pb = emp + (size_t)(128 + b) * 4608;
    for (int i = tid; i < 4608; i += 256) {
        unsigned q = ((unsigned)i * 7282u) >> 16;          // i/9 for i<4608
        em[i] = pf[i] + pb[i] + bout[i - 9 * q];
    }
    for (int i = tid; i < 512; i += 256) msk[i] = mask[b * 512 + i];
    __syncthreads();

    if (tid < 64) {   // wave 0: forward DP
        const int k = (tid < NT) ? tid : 0;
        float trk[9];
#pragma unroll
        for (int j = 0; j < NT; ++j) trk[j] = trans[j * 9 + k];
        float score = startt[k] + em[k];
        for (int t = 1; t < 512; ++t) {
            float v[9];
#pragma unroll
            for (int j = 0; j < NT; ++j) v[j] = __shfl(score, j, 64) + trk[j];
            float m01 = fmaxf(v[0], v[1]), m23 = fmaxf(v[2], v[3]);
            float m45 = fmaxf(v[4], v[5]), m67 = fmaxf(v[6], v[7]);
            float m = fmaxf(fmaxf(fmaxf(m01, m23), fmaxf(m45, m67)), v[8]);
            int bi = 0;
#pragma unroll
            for (int j = 8; j >= 0; --j) if (v[j] == m) bi = j;   // first index
            if (msk[t]) score = m + em[t * 9 + k];
            if (tid < NT) hist[t * 9 + tid] = (unsigned char)bi;
        }
        float fin = score + endt[k];
        float bs = -3e38f; int cur = 0;
#pragma unroll
        for (int j = 0; j < NT; ++j) {
            float vv = __shfl(fin, j, 64);
            if (vv > bs) { bs = vv; cur = j; }
        }
        if (tid == 0) { curS = cur; out[65536 + b] = bs; }
    }
    __syncthreads();

    // block composition maps: block m covers t in [16m+1, min(16m+16,511)]
    if (tid < 32) {
        const int m = tid;
        int G[9];
#pragma unroll
        for (int k = 0; k < NT; ++k) G[k] = k;
        const int hi = (m == 31) ? 511 : (16 * m + 16);
        for (int t = hi; t >= 16 * m + 1; --t) {
            if (msk[t]) {
#pragma unroll
                for (int k = 0; k < NT; ++k) G[k] = hist[t * 9 + G[k]];
            }
        }
#pragma unroll
        for (int k = 0; k < NT; ++k) Gl[m * 12 + k] = (unsigned char)G[k];
    }
    __syncthreads();

    if (tid == 0) {   // serial boundary walk (31 steps)
        int e = curS;
        bound[31] = (unsigned char)e;
        for (int m = 31; m >= 1; --m) { e = Gl[m * 12 + e]; bound[m - 1] = (unsigned char)e; }
        out[(size_t)b * 512] = (float)Gl[0 * 12 + e];   // c_0
    }
    __syncthreads();

    if (tid < 32) {   // lane-parallel interior backtrace
        const int m = tid;
        int ccur = bound[m];
        const int hi = (m == 31) ? 511 : (16 * m + 16);
        for (int t = hi; t >= 16 * m + 1; --t) {
            const int mt = msk[t];
            out[(size_t)b * 512 + t] = (float)(mt ? ccur : -1);
            if (mt) ccur = hist[t * 9 + ccur];
        }
    }
}

// ---------------------------------------------------------------------------
extern "C" void kernel_launch(void* const* d_in, const int* in_sizes, int n_in,
                              void* d_out, int out_size, void* d_ws, size_t ws_size,
                              hipStream_t stream) {
    const int*   x      = (const int*)d_in[0];
    const int*   mask   = (const int*)d_in[1];
    const float* embed  = (const float*)d_in[2];
    const float* Wihf   = (const float*)d_in[3];
    const float* Whhf   = (const float*)d_in[4];
    const float* bf_    = (const float*)d_in[5];
    const float* Wihb   = (const float*)d_in[6];
    const float* Whhb   = (const float*)d_in[7];
    const float* bb_    = (const float*)d_in[8];
    const float* Wout   = (const float*)d_in[9];
    const float* bout   = (const float*)d_in[10];
    const float* startt = (const float*)d_in[11];
    const float* trans  = (const float*)d_in[12];
    const float* endt   = (const float*)d_in[13];

    unsigned short* xg    = (unsigned short*)d_ws;                        // 128 MB bf16
    float*          emp   = (float*)((char*)d_ws + (size_t)134217728);    // 4.5 MB f32
    unsigned short* feats = (unsigned short*)((char*)d_ws + (size_t)138936320); // 32 MB bf16
    float*          out   = (float*)d_out;

    k_xg     <<<dim3(512, 2), 512, 0, stream>>>(x, embed, Wihf, bf_, Wihb, bb_, xg);
    k_lstm   <<<dim3(32, 2),  512, 0, stream>>>(xg, Whhf, Whhb, feats);
    k_emis   <<<1024,         256, 0, stream>>>(feats, Wout, emp);
    k_viterbi<<<128,          256, 0, stream>>>(emp, mask, bout, startt, trans, endt, out);
}